// Round 1
// baseline (840.446 us; speedup 1.0000x reference)
//
#include <hip/hip_runtime.h>

#define R 32
#define PCHUNK 200

// ws layout: ws[0:32] = s1 = colsum(U1), ws[32:64] = s0 = colsum(U0)
__global__ __launch_bounds__(1024) void colsum_kernel(
    const float* __restrict__ U0, int n0rows,
    const float* __restrict__ U1, int n1rows,
    float* __restrict__ ws)
{
    const float* U = (blockIdx.x == 0) ? U1 : U0;
    int rows       = (blockIdx.x == 0) ? n1rows : n0rows;
    float* out     = ws + blockIdx.x * R;

    int c = threadIdx.x & (R - 1);   // column 0..31
    int g = threadIdx.x >> 5;        // group 0..31

    float acc = 0.f;
    for (int r = g; r < rows; r += 32)
        acc += U[(size_t)r * R + c];

    __shared__ float red[32][R + 1];
    red[g][c] = acc;
    __syncthreads();
    for (int off = 16; off > 0; off >>= 1) {
        if (g < off) red[g][c] += red[g + off][c];
        __syncthreads();
    }
    if (g == 0) out[c] = red[0][c];
}

// Each lane owns 2 consecutive output columns; per-lane registers hold
// s[k]*U[n][k] (scale folded in, loop-invariant). p is wave-uniform so
// pt loads scalarize to s_load; only VMEM traffic is the streaming store.
__global__ __launch_bounds__(256) void mode_kernel(
    const float* __restrict__ pt,   // [P][R]
    const float* __restrict__ U,    // [N][R]
    const float* __restrict__ s,    // [R]
    float* __restrict__ V,          // [P][N]
    int N, int P)
{
    const int lane = threadIdx.x & 63;
    const int wave = threadIdx.x >> 6;
    const int slot = (blockIdx.x * 4 + wave) * 64 + lane;  // float2 slot
    const int nslots = N >> 1;
    const bool active = (slot < nslots);
    const int n0 = (active ? slot : 0) * 2;                // clamped for loads

    float ua[R], ub[R];
    {
        const float4* Ua = (const float4*)(U + (size_t)n0 * R);
        const float4* Ub = (const float4*)(U + (size_t)(n0 + 1) * R);
        const float4* S4 = (const float4*)s;
#pragma unroll
        for (int i = 0; i < R / 4; ++i) {
            float4 sv = S4[i];
            float4 x = Ua[i];
            float4 y = Ub[i];
            ua[4*i+0] = x.x * sv.x; ua[4*i+1] = x.y * sv.y;
            ua[4*i+2] = x.z * sv.z; ua[4*i+3] = x.w * sv.w;
            ub[4*i+0] = y.x * sv.x; ub[4*i+1] = y.y * sv.y;
            ub[4*i+2] = y.z * sv.z; ub[4*i+3] = y.w * sv.w;
        }
    }

    int p0 = blockIdx.y * PCHUNK;
    int p1 = min(p0 + PCHUNK, P);
    for (int p = p0; p < p1; ++p) {
        const float4* A4 = (const float4*)(pt + (size_t)p * R);
        float ax0 = 0.f, ax1 = 0.f, ay0 = 0.f, ay1 = 0.f;
#pragma unroll
        for (int i = 0; i < R / 4; ++i) {
            float4 a = A4[i];   // wave-uniform -> s_load_dwordx4
            ax0 += a.x * ua[4*i+0] + a.y * ua[4*i+1];
            ax1 += a.z * ua[4*i+2] + a.w * ua[4*i+3];
            ay0 += a.x * ub[4*i+0] + a.y * ub[4*i+1];
            ay1 += a.z * ub[4*i+2] + a.w * ub[4*i+3];
        }
        if (active) {
            float2 v = make_float2(ax0 + ax1, ay0 + ay1);
            union { float2 f2; double d; } cvt;
            cvt.f2 = v;
            // streaming 600 MB of output: keep it out of L2
            __builtin_nontemporal_store(cvt.d, (double*)(V + (size_t)p * N + n0));
        }
    }
}

extern "C" void kernel_launch(void* const* d_in, const int* in_sizes, int n_in,
                              void* d_out, int out_size, void* d_ws, size_t ws_size,
                              hipStream_t stream) {
    const float* pt = (const float*)d_in[0];
    const float* U0 = (const float*)d_in[1];
    const float* U1 = (const float*)d_in[2];
    int P  = in_sizes[0] / R;   // 50000
    int N0 = in_sizes[1] / R;   // 2000
    int N1 = in_sizes[2] / R;   // 1000

    float* ws  = (float*)d_ws;
    float* out = (float*)d_out;

    colsum_kernel<<<dim3(2), dim3(1024), 0, stream>>>(U0, N0, U1, N1, ws);

    int gy  = (P + PCHUNK - 1) / PCHUNK;           // 250
    int gx0 = ((N0 / 2) + 255) / 256;              // 4
    int gx1 = ((N1 / 2) + 255) / 256;              // 2
    // V0 = (pt * s1) @ U0^T   (s1 at ws+0)
    mode_kernel<<<dim3(gx0, gy), dim3(256), 0, stream>>>(pt, U0, ws, out, N0, P);
    // V1 = (pt * s0) @ U1^T   (s0 at ws+32)
    mode_kernel<<<dim3(gx1, gy), dim3(256), 0, stream>>>(pt, U1, ws + R,
                                                         out + (size_t)P * N0, N1, P);
}